// Round 3
// baseline (422.079 us; speedup 1.0000x reference)
//
#include <hip/hip_runtime.h>
#include <cstdint>
#include <cstddef>

#define DEVI __device__ __forceinline__

typedef __attribute__((ext_vector_type(8))) short short8;
typedef __attribute__((ext_vector_type(4))) float f32x4;

constexpr int Bc = 8, Tc = 2048, Cc = 1024;
constexpr int WKV_L = 32, WKV_NCH = 64;   // T = L * NCH

DEVI unsigned short f2b(float f) {
  unsigned int u = __float_as_uint(f);
  unsigned int r = (u + 0x7FFFu + ((u >> 16) & 1u)) >> 16;  // RNE
  return (unsigned short)r;
}

DEVI void gload16(const unsigned short* g, unsigned short* l) {
  __builtin_amdgcn_global_load_lds(
      (const __attribute__((address_space(1))) void*)g,
      (__attribute__((address_space(3))) void*)l, 16, 0, 0);
}

// ---------------- f32 -> bf16 convert (Wo) ----------------
__global__ void convert_bf16_kernel(const float* __restrict__ in,
                                    unsigned short* __restrict__ out, int n4) {
  int i = blockIdx.x * blockDim.x + threadIdx.x;
  if (i >= n4) return;
  const float4 v = ((const float4*)in)[i];
  ushort4 o;
  o.x = f2b(v.x); o.y = f2b(v.y); o.z = f2b(v.z); o.w = f2b(v.w);
  ((ushort4*)out)[i] = o;
}

// ---------------- fused-mix weight prep ----------------
// Wf [3072][2048] bf16: rows 0-1023 Wk, 1024-2047 Wv, 2048-3071 Wr.
// cols 0-1023: W[n][c]*mix[c]; cols 1024-2047: W[n][c-1024]*(1-mix[c-1024]).
__global__ void wprep_kernel(const float* __restrict__ Wk,
                             const float* __restrict__ Wv,
                             const float* __restrict__ Wr,
                             const float* __restrict__ tmk,
                             const float* __restrict__ tmv,
                             const float* __restrict__ tmr,
                             unsigned short* __restrict__ Wf) {
  const long i = (long)blockIdx.x * blockDim.x + threadIdx.x;
  const long e = i * 4;                   // element index in Wf
  const int c2 = (int)(e & 2047);
  const int n = (int)(e >> 11);           // 0..3071
  const int sel = n >> 10;
  const int nr = n & 1023;
  const float* W = sel == 0 ? Wk : (sel == 1 ? Wv : Wr);
  const float* tm = sel == 0 ? tmk : (sel == 1 ? tmv : tmr);
  const int c = c2 & 1023;
  const bool second = c2 >= 1024;
  const float4 wv = *(const float4*)(W + (size_t)nr * 1024 + c);
  const float4 mv = *(const float4*)(tm + c);
  const float* wp = (const float*)&wv;
  const float* mp = (const float*)&mv;
  ushort4 o;
  unsigned short* op = (unsigned short*)&o;
#pragma unroll
  for (int q = 0; q < 4; ++q) {
    const float m = second ? (1.f - mp[q]) : mp[q];
    op[q] = f2b(wp[q] * m);
  }
  *(ushort4*)(Wf + e) = o;
}

// ---------------- y = [bf16(x), bf16(prev_x)] [16384][2048] ----------------
__global__ void ybuild_kernel(const float* __restrict__ x,
                              unsigned short* __restrict__ y, long n4) {
  long i = (long)blockIdx.x * blockDim.x + threadIdx.x;
  const long stride = (long)gridDim.x * blockDim.x;
  for (; i < n4; i += stride) {
    const long e = i * 4;                 // element index in x
    const int c = (int)(e & 1023);
    const long bt = e >> 10;
    const int t = (int)(bt & (Tc - 1));
    const float4 xv = *(const float4*)(x + e);
    float4 pv = {0.f, 0.f, 0.f, 0.f};
    if (t > 0) pv = *(const float4*)(x + e - Cc);
    const float* xp = (const float*)&xv;
    const float* pp = (const float*)&pv;
    ushort4 xo, po;
    unsigned short* xop = (unsigned short*)&xo;
    unsigned short* pop = (unsigned short*)&po;
#pragma unroll
    for (int q = 0; q < 4; ++q) { xop[q] = f2b(xp[q]); pop[q] = f2b(pp[q]); }
    *(ushort4*)(y + bt * 2048 + c) = xo;
    *(ushort4*)(y + bt * 2048 + 1024 + c) = po;
  }
}

// ---------------- 2-phase prefetch bf16 GEMM ----------------
// C[M][*] = A[M][K] * W[N][K]^T, f32 out. Output cols < ncut -> C0 (ldc0),
// cols >= ncut -> C1 (ldc1, col-offset by ncut). 128x128 tile, BK=32,
// double-buffered LDS, STAGE(next) issued before compute (T3-min).
__global__ __launch_bounds__(256)
void gemm_bf16_2ph(const unsigned short* __restrict__ A,
                   const unsigned short* __restrict__ W,
                   int K,
                   float* __restrict__ C0, int ldc0, int ncut,
                   float* __restrict__ C1, int ldc1) {
  constexpr int BM = 128, BN = 128, BK = 32;
  __shared__ alignas(16) unsigned short As[2][BM * BK];
  __shared__ alignas(16) unsigned short Bs[2][BN * BK];
  const int m0 = blockIdx.x * BM;
  const int n0 = blockIdx.y * BN;
  const int tid = threadIdx.x;
  const int lane = tid & 63;
  const int w = tid >> 6;
  const int wr = w >> 1, wc = w & 1;
  const int fr = lane & 15;
  const int fk = (lane >> 4) * 8;
  // staging geometry: chunk index for this lane in each of 2 rounds
  const int ch0 = (w * 2 + 0) * 64 + lane;
  const int ch1 = (w * 2 + 1) * 64 + lane;

  f32x4 acc[4][4];
#pragma unroll
  for (int i = 0; i < 4; ++i)
#pragma unroll
    for (int j = 0; j < 4; ++j) acc[i][j] = (f32x4){0.f, 0.f, 0.f, 0.f};

#define STAGE(buf, kt)                                                        \
  {                                                                           \
    const int r0 = ch0 >> 2, c0_ = ch0 & 3;                                   \
    const int r1 = ch1 >> 2, c1_ = ch1 & 3;                                   \
    gload16(A + (size_t)(m0 + r0) * K + (kt) + c0_ * 8,                       \
            &As[buf][(w * 2 + 0) * 512]);                                     \
    gload16(W + (size_t)(n0 + r0) * K + (kt) + c0_ * 8,                       \
            &Bs[buf][(w * 2 + 0) * 512]);                                     \
    gload16(A + (size_t)(m0 + r1) * K + (kt) + c1_ * 8,                       \
            &As[buf][(w * 2 + 1) * 512]);                                     \
    gload16(W + (size_t)(n0 + r1) * K + (kt) + c1_ * 8,                       \
            &Bs[buf][(w * 2 + 1) * 512]);                                     \
  }

  STAGE(0, 0);
  __syncthreads();
  int cur = 0;
  const int nt = K / BK;
  for (int t = 0; t < nt; ++t) {
    if (t + 1 < nt) STAGE(cur ^ 1, (t + 1) * BK);
    short8 af[4], bfr[4];
#pragma unroll
    for (int i = 0; i < 4; ++i) {
      af[i]  = *(const short8*)&As[cur][(wr * 64 + i * 16 + fr) * BK + fk];
      bfr[i] = *(const short8*)&Bs[cur][(wc * 64 + i * 16 + fr) * BK + fk];
    }
#pragma unroll
    for (int i = 0; i < 4; ++i)
#pragma unroll
      for (int j = 0; j < 4; ++j)
        acc[i][j] = __builtin_amdgcn_mfma_f32_16x16x32_bf16(af[i], bfr[j],
                                                            acc[i][j], 0, 0, 0);
    __syncthreads();   // drains vmcnt(0): next buffer staged; lgkm: reads done
    cur ^= 1;
  }
#undef STAGE

  float* Cp; int ldc, col0;
  if (n0 < ncut) { Cp = C0; ldc = ldc0; col0 = n0; }
  else           { Cp = C1; ldc = ldc1; col0 = n0 - ncut; }
  const int orow = (lane >> 4) * 4;
  const int ocol = lane & 15;
#pragma unroll
  for (int i = 0; i < 4; ++i)
#pragma unroll
    for (int j = 0; j < 4; ++j) {
      const size_t rbase = (size_t)(m0 + wr * 64 + i * 16 + orow);
      const int cb = col0 + wc * 64 + j * 16 + ocol;
#pragma unroll
      for (int q = 0; q < 4; ++q)
        Cp[(rbase + q) * ldc + cb] = acc[i][j][q];
    }
}

// ---------------- WKV chunked scan ----------------
// kv buffer: [16384][2048] f32, cols 0-1023 = key, 1024-2047 = value.

__global__ void wkv_phase1(const float* __restrict__ kv,
                           const float* __restrict__ td,
                           float* __restrict__ s_num,
                           float* __restrict__ s_den,
                           float* __restrict__ s_mx) {
  const int g = blockIdx.x * blockDim.x + threadIdx.x;  // [0, B*NCH*C)
  const int c = g & (Cc - 1);
  const int j = (g / Cc) & (WKV_NCH - 1);
  const int b = g / (Cc * WKV_NCH);
  const float w = -__expf(td[c]);
  float num = 0.f, den = 0.f, mx = -1e38f;
  size_t row = (size_t)b * Tc + (size_t)j * WKV_L;
#pragma unroll 4
  for (int i = 0; i < WKV_L; ++i, ++row) {
    const float kt = kv[row * 2048 + c];
    const float vt = kv[row * 2048 + 1024 + c];
    const float mw = mx + w;
    const float mn = fmaxf(mw, kt);
    const float a1 = __expf(mw - mn);
    const float a2 = __expf(kt - mn);
    num = a1 * num + a2 * vt;
    den = a1 * den + a2;
    mx = mn;
  }
  s_num[g] = num; s_den[g] = den; s_mx[g] = mx;
}

__global__ void wkv_phase2(const float* __restrict__ td,
                           float* __restrict__ s_num,
                           float* __restrict__ s_den,
                           float* __restrict__ s_mx) {
  const int g = blockIdx.x * blockDim.x + threadIdx.x;  // [0, B*C)
  const int c = g & (Cc - 1);
  const int b = g / Cc;
  const float Lw = -__expf(td[c]) * (float)WKV_L;
  float num = 0.f, den = 0.f, mx = -1e38f;
  size_t base = (size_t)b * WKV_NCH * Cc + c;
  for (int j = 0; j < WKV_NCH; ++j) {
    const size_t s = base + (size_t)j * Cc;
    const float ln = s_num[s], ld = s_den[s], lm = s_mx[s];
    s_num[s] = num; s_den[s] = den; s_mx[s] = mx;  // exclusive prefix
    const float md = mx + Lw;
    const float m = fmaxf(md, lm);
    const float e1 = __expf(md - m);
    const float e2 = __expf(lm - m);
    num = e1 * num + e2 * ln;
    den = e1 * den + e2 * ld;
    mx = m;
  }
}

__global__ void wkv_phase3(const float* __restrict__ kv,
                           const float* __restrict__ rec,
                           const float* __restrict__ td,
                           const float* __restrict__ tf,
                           const float* __restrict__ s_num,
                           const float* __restrict__ s_den,
                           const float* __restrict__ s_mx,
                           unsigned short* __restrict__ rwkv) {
  const int g = blockIdx.x * blockDim.x + threadIdx.x;  // [0, B*NCH*C)
  const int c = g & (Cc - 1);
  const int j = (g / Cc) & (WKV_NCH - 1);
  const int b = g / (Cc * WKV_NCH);
  const float w = -__expf(td[c]);
  const float u = tf[c];
  float num = s_num[g], den = s_den[g], mx = s_mx[g];
  size_t row = (size_t)b * Tc + (size_t)j * WKV_L;
#pragma unroll 2
  for (int i = 0; i < WKV_L; ++i, ++row) {
    const float kt = kv[row * 2048 + c];
    const float vt = kv[row * 2048 + 1024 + c];
    const float rt = rec[row * 1024 + c];
    const float ku = kt + u;
    const float mo = fmaxf(mx, ku);
    const float e1 = __expf(mx - mo);
    const float e2 = __expf(ku - mo);
    const float out = (e1 * num + e2 * vt) / (e1 * den + e2);
    const float sr = 1.f / (1.f + __expf(-rt));
    rwkv[row * 1024 + c] = f2b(sr * out);
    const float mw = mx + w;
    const float mn = fmaxf(mw, kt);
    const float a1 = __expf(mw - mn);
    const float a2 = __expf(kt - mn);
    num = a1 * num + a2 * vt;
    den = a1 * den + a2;
    mx = mn;
  }
}

extern "C" void kernel_launch(void* const* d_in, const int* in_sizes, int n_in,
                              void* d_out, int out_size, void* d_ws, size_t ws_size,
                              hipStream_t stream) {
  const float* x   = (const float*)d_in[0];
  const float* Wk  = (const float*)d_in[1];
  const float* Wv  = (const float*)d_in[2];
  const float* Wr  = (const float*)d_in[3];
  const float* Wo  = (const float*)d_in[4];
  const float* td  = (const float*)d_in[5];
  const float* tf  = (const float*)d_in[6];
  const float* tmk = (const float*)d_in[7];
  const float* tmv = (const float*)d_in[8];
  const float* tmr = (const float*)d_in[9];

  const long BT = (long)Bc * Tc;     // 16384
  const long NE = BT * Cc;           // 16,777,216

  // Workspace carve (~213 MB)
  char* p = (char*)d_ws;
  unsigned short* Wf   = (unsigned short*)p; p += (long)3072 * 2048 * 2;  // 12.6 MB
  unsigned short* Wo_b = (unsigned short*)p; p += (long)Cc * Cc * 2;      // 2 MB
  unsigned short* y    = (unsigned short*)p; p += BT * 2048 * 2;          // 64 MB
  float* kv            = (float*)p;          p += BT * 2048 * 4;          // 134 MB
  // aliases into y region (y dead after fused GEMM):
  unsigned short* rwkv = y;                                  // 32 MB
  const long NS = (long)Bc * WKV_NCH * Cc;                   // 524288
  float* s_num = (float*)((char*)y + (size_t)34 * 1024 * 1024);
  float* s_den = s_num + NS;
  float* s_mx  = s_den + NS;
  float* recf  = (float*)d_out;   // receptance f32, dead before final GEMM

  // 1. weight prep
  wprep_kernel<<<6144, 256, 0, stream>>>(Wk, Wv, Wr, tmk, tmv, tmr, Wf);
  convert_bf16_kernel<<<1024, 256, 0, stream>>>(Wo, Wo_b, (int)(Cc * Cc / 4));

  // 2. y = [x, prev_x] bf16
  ybuild_kernel<<<2048, 256, 0, stream>>>(x, y, NE / 4);

  // 3. fused QKVR GEMM: [16384x2048] @ [3072x2048]^T
  //    cols 0-2047 (k,v) -> kv buf; cols 2048-3071 (r) -> d_out
  {
    dim3 grid(128, 24), blk(256);
    gemm_bf16_2ph<<<grid, blk, 0, stream>>>(y, Wf, 2048, kv, 2048, 2048,
                                            recf, 1024);
  }

  // 4. WKV chunked scan + sigmoid gate -> rwkv bf16
  wkv_phase1<<<2048, 256, 0, stream>>>(kv, td, s_num, s_den, s_mx);
  wkv_phase2<<<32, 256, 0, stream>>>(td, s_num, s_den, s_mx);
  wkv_phase3<<<2048, 256, 0, stream>>>(kv, recf, td, tf, s_num, s_den, s_mx, rwkv);

  // 5. output GEMM -> d_out
  {
    dim3 grid(128, 8), blk(256);
    gemm_bf16_2ph<<<grid, blk, 0, stream>>>(rwkv, Wo_b, 1024, (float*)d_out,
                                            1024, 1024, (float*)d_out, 1024);
  }
}

// Round 4
// 307.357 us; speedup vs baseline: 1.3733x; 1.3733x over previous
//
#include <hip/hip_runtime.h>
#include <cstdint>
#include <cstddef>

#define DEVI __device__ __forceinline__

typedef __attribute__((ext_vector_type(8))) short short8;
typedef __attribute__((ext_vector_type(4))) float f32x4;

constexpr int Bc = 8, Tc = 2048, Cc = 1024;
constexpr int WKV_L = 32, WKV_NCH = 64;   // T = L * NCH

DEVI unsigned short f2b(float f) {
  unsigned int u = __float_as_uint(f);
  unsigned int r = (u + 0x7FFFu + ((u >> 16) & 1u)) >> 16;  // RNE
  return (unsigned short)r;
}
DEVI float b2f(unsigned short u) {
  return __uint_as_float(((unsigned int)u) << 16);
}

DEVI void gload16(const unsigned short* g, unsigned short* l) {
  __builtin_amdgcn_global_load_lds(
      (const __attribute__((address_space(1))) void*)g,
      (__attribute__((address_space(3))) void*)l, 16, 0, 0);
}

// ---------------- f32 -> bf16 convert (weights) ----------------
__global__ void convert_bf16_kernel(const float* __restrict__ in,
                                    unsigned short* __restrict__ out, int n4) {
  int i = blockIdx.x * blockDim.x + threadIdx.x;
  if (i >= n4) return;
  const float4 v = ((const float4*)in)[i];
  ushort4 o;
  o.x = f2b(v.x); o.y = f2b(v.y); o.z = f2b(v.z); o.w = f2b(v.w);
  ((ushort4*)out)[i] = o;
}

// ---------------- time-mix (k,v,r) + bf16 cast ----------------
__global__ void mix3_kernel(const float* __restrict__ x,
                            const float* __restrict__ tmk,
                            const float* __restrict__ tmv,
                            const float* __restrict__ tmr,
                            unsigned short* __restrict__ kin,
                            unsigned short* __restrict__ vin,
                            unsigned short* __restrict__ rin,
                            long n4) {
  long i = (long)blockIdx.x * blockDim.x + threadIdx.x;
  const long stride = (long)gridDim.x * blockDim.x;
  for (; i < n4; i += stride) {
    const long e = i * 4;
    const int c = (int)(e & (Cc - 1));
    const long bt = e >> 10;
    const int t = (int)(bt & (Tc - 1));
    const float4 xv = *(const float4*)(x + e);
    float4 pv = {0.f, 0.f, 0.f, 0.f};
    if (t > 0) pv = *(const float4*)(x + e - Cc);
    const float4 mk = *(const float4*)(tmk + c);
    const float4 mv = *(const float4*)(tmv + c);
    const float4 mr = *(const float4*)(tmr + c);
    const float* xp = (const float*)&xv;
    const float* pp = (const float*)&pv;
    const float* mkp = (const float*)&mk;
    const float* mvp = (const float*)&mv;
    const float* mrp = (const float*)&mr;
    ushort4 ko, vo, ro;
    unsigned short* kop = (unsigned short*)&ko;
    unsigned short* vop = (unsigned short*)&vo;
    unsigned short* rop = (unsigned short*)&ro;
#pragma unroll
    for (int q = 0; q < 4; ++q) {
      kop[q] = f2b(xp[q] * mkp[q] + pp[q] * (1.f - mkp[q]));
      vop[q] = f2b(xp[q] * mvp[q] + pp[q] * (1.f - mvp[q]));
      rop[q] = f2b(xp[q] * mrp[q] + pp[q] * (1.f - mrp[q]));
    }
    *(ushort4*)(kin + e) = ko;
    *(ushort4*)(vin + e) = vo;
    *(ushort4*)(rin + e) = ro;
  }
}

// ---------------- 2-phase prefetch bf16 GEMM, T2-swizzled LDS ----------------
// C[M][N] = A[M][K] * W[N][K]^T. 128x128 tile, BK=32, dbuf LDS.
// LDS tile layout: [row][4 slots of 16B]; physical slot p = s ^ (row&3).
// STAGE pre-swizzles the GLOBAL source column (LDS dest linear, rule #21);
// ds_read applies the same involution.
template <typename OutT>
__global__ __launch_bounds__(256)
void gemm_bf16_2ph(const unsigned short* __restrict__ A,
                   const unsigned short* __restrict__ W,
                   OutT* __restrict__ C_out, int K, int N) {
  constexpr int BK = 32;
  __shared__ alignas(16) unsigned short As[2][128 * BK];
  __shared__ alignas(16) unsigned short Bs[2][128 * BK];
  const int m0 = blockIdx.x * 128;
  const int n0 = blockIdx.y * 128;
  const int tid = threadIdx.x;
  const int lane = tid & 63;
  const int w = tid >> 6;
  const int wr = w >> 1, wc = w & 1;
  const int fr = lane & 15;
  const int sA = lane >> 4;              // logical 16B k-slot, 0..3
  // staging geometry: 512 chunks of 16B per tile; this thread's 2 chunks
  const int ch0 = (w * 2 + 0) * 64 + lane;
  const int ch1 = (w * 2 + 1) * 64 + lane;
  const int r0 = ch0 >> 2, g0 = (ch0 & 3) ^ (r0 & 3);   // swizzled global slot
  const int r1 = ch1 >> 2, g1 = (ch1 & 3) ^ (r1 & 3);

  f32x4 acc[4][4];
#pragma unroll
  for (int i = 0; i < 4; ++i)
#pragma unroll
    for (int j = 0; j < 4; ++j) acc[i][j] = (f32x4){0.f, 0.f, 0.f, 0.f};

#define STAGE(buf, kt)                                                        \
  {                                                                           \
    gload16(A + (size_t)(m0 + r0) * K + (kt) + g0 * 8, &As[buf][ch0 * 8]);    \
    gload16(W + (size_t)(n0 + r0) * K + (kt) + g0 * 8, &Bs[buf][ch0 * 8]);    \
    gload16(A + (size_t)(m0 + r1) * K + (kt) + g1 * 8, &As[buf][ch1 * 8]);    \
    gload16(W + (size_t)(n0 + r1) * K + (kt) + g1 * 8, &Bs[buf][ch1 * 8]);    \
  }

  STAGE(0, 0);
  __syncthreads();
  int cur = 0;
  const int nt = K / BK;
  for (int t = 0; t < nt; ++t) {
    if (t + 1 < nt) STAGE(cur ^ 1, (t + 1) * BK);
    short8 af[4], bfr[4];
#pragma unroll
    for (int i = 0; i < 4; ++i) {
      const int ra = wr * 64 + i * 16 + fr;
      const int rb = wc * 64 + i * 16 + fr;
      af[i]  = *(const short8*)&As[cur][ra * 32 + ((sA ^ (ra & 3)) * 8)];
      bfr[i] = *(const short8*)&Bs[cur][rb * 32 + ((sA ^ (rb & 3)) * 8)];
    }
#pragma unroll
    for (int i = 0; i < 4; ++i)
#pragma unroll
      for (int j = 0; j < 4; ++j)
        acc[i][j] = __builtin_amdgcn_mfma_f32_16x16x32_bf16(af[i], bfr[j],
                                                            acc[i][j], 0, 0, 0);
    __syncthreads();   // drains vmcnt(0): next buffer staged; lgkm: reads done
    cur ^= 1;
  }
#undef STAGE

  const int orow = (lane >> 4) * 4;
  const int ocol = lane & 15;
#pragma unroll
  for (int i = 0; i < 4; ++i)
#pragma unroll
    for (int j = 0; j < 4; ++j) {
      const size_t rbase = (size_t)(m0 + wr * 64 + i * 16 + orow);
      const int cb = n0 + wc * 64 + j * 16 + ocol;
#pragma unroll
      for (int q = 0; q < 4; ++q) {
        const float vq = acc[i][j][q];
        if constexpr (sizeof(OutT) == 2)
          C_out[(rbase + q) * N + cb] = (OutT)f2b(vq);
        else
          C_out[(rbase + q) * N + cb] = (OutT)vq;
      }
    }
}

// ---------------- WKV chunked scan (bf16 inputs) ----------------
__global__ void wkv_phase1(const unsigned short* __restrict__ keyb,
                           const unsigned short* __restrict__ valb,
                           const float* __restrict__ td,
                           float* __restrict__ s_num,
                           float* __restrict__ s_den,
                           float* __restrict__ s_mx) {
  const int g = blockIdx.x * blockDim.x + threadIdx.x;  // [0, B*NCH*C)
  const int c = g & (Cc - 1);
  const int j = (g / Cc) & (WKV_NCH - 1);
  const int b = g / (Cc * WKV_NCH);
  const float w = -__expf(td[c]);
  float num = 0.f, den = 0.f, mx = -1e38f;
  size_t idx = ((size_t)b * Tc + (size_t)j * WKV_L) * Cc + c;
#pragma unroll 4
  for (int i = 0; i < WKV_L; ++i, idx += Cc) {
    const float kt = b2f(keyb[idx]);
    const float vt = b2f(valb[idx]);
    const float mw = mx + w;
    const float mn = fmaxf(mw, kt);
    const float a1 = __expf(mw - mn);
    const float a2 = __expf(kt - mn);
    num = a1 * num + a2 * vt;
    den = a1 * den + a2;
    mx = mn;
  }
  s_num[g] = num; s_den[g] = den; s_mx[g] = mx;
}

__global__ void wkv_phase2(const float* __restrict__ td,
                           float* __restrict__ s_num,
                           float* __restrict__ s_den,
                           float* __restrict__ s_mx) {
  const int g = blockIdx.x * blockDim.x + threadIdx.x;  // [0, B*C)
  const int c = g & (Cc - 1);
  const int b = g / Cc;
  const float Lw = -__expf(td[c]) * (float)WKV_L;
  float num = 0.f, den = 0.f, mx = -1e38f;
  size_t base = (size_t)b * WKV_NCH * Cc + c;
  for (int j = 0; j < WKV_NCH; ++j) {
    const size_t s = base + (size_t)j * Cc;
    const float ln = s_num[s], ld = s_den[s], lm = s_mx[s];
    s_num[s] = num; s_den[s] = den; s_mx[s] = mx;  // exclusive prefix
    const float md = mx + Lw;
    const float m = fmaxf(md, lm);
    const float e1 = __expf(md - m);
    const float e2 = __expf(lm - m);
    num = e1 * num + e2 * ln;
    den = e1 * den + e2 * ld;
    mx = m;
  }
}

__global__ void wkv_phase3(const unsigned short* __restrict__ keyb,
                           const unsigned short* __restrict__ valb,
                           const unsigned short* __restrict__ recb,
                           const float* __restrict__ td,
                           const float* __restrict__ tf,
                           const float* __restrict__ s_num,
                           const float* __restrict__ s_den,
                           const float* __restrict__ s_mx,
                           unsigned short* __restrict__ rwkv) {
  const int g = blockIdx.x * blockDim.x + threadIdx.x;  // [0, B*NCH*C)
  const int c = g & (Cc - 1);
  const int j = (g / Cc) & (WKV_NCH - 1);
  const int b = g / (Cc * WKV_NCH);
  const float w = -__expf(td[c]);
  const float u = tf[c];
  float num = s_num[g], den = s_den[g], mx = s_mx[g];
  size_t idx = ((size_t)b * Tc + (size_t)j * WKV_L) * Cc + c;
#pragma unroll 2
  for (int i = 0; i < WKV_L; ++i, idx += Cc) {
    const float kt = b2f(keyb[idx]);
    const float vt = b2f(valb[idx]);
    const float rt = b2f(recb[idx]);
    const float ku = kt + u;
    const float mo = fmaxf(mx, ku);
    const float e1 = __expf(mx - mo);
    const float e2 = __expf(ku - mo);
    const float out = (e1 * num + e2 * vt) / (e1 * den + e2);
    const float sr = 1.f / (1.f + __expf(-rt));
    rwkv[idx] = f2b(sr * out);
    const float mw = mx + w;
    const float mn = fmaxf(mw, kt);
    const float a1 = __expf(mw - mn);
    const float a2 = __expf(kt - mn);
    num = a1 * num + a2 * vt;
    den = a1 * den + a2;
    mx = mn;
  }
}

extern "C" void kernel_launch(void* const* d_in, const int* in_sizes, int n_in,
                              void* d_out, int out_size, void* d_ws, size_t ws_size,
                              hipStream_t stream) {
  const float* x   = (const float*)d_in[0];
  const float* Wk  = (const float*)d_in[1];
  const float* Wv  = (const float*)d_in[2];
  const float* Wr  = (const float*)d_in[3];
  const float* Wo  = (const float*)d_in[4];
  const float* td  = (const float*)d_in[5];
  const float* tf  = (const float*)d_in[6];
  const float* tmk = (const float*)d_in[7];
  const float* tmv = (const float*)d_in[8];
  const float* tmr = (const float*)d_in[9];

  const long BT = (long)Bc * Tc;     // 16384
  const long NE = BT * Cc;           // 16,777,216
  const long CC = (long)Cc * Cc;     // 1,048,576

  // Workspace carve (~200 MB)
  char* p = (char*)d_ws;
  unsigned short* Wk_b = (unsigned short*)p; p += CC * 2;
  unsigned short* Wv_b = (unsigned short*)p; p += CC * 2;
  unsigned short* Wr_b = (unsigned short*)p; p += CC * 2;
  unsigned short* Wo_b = (unsigned short*)p; p += CC * 2;
  unsigned short* kin  = (unsigned short*)p; p += NE * 2;
  unsigned short* vin  = (unsigned short*)p; p += NE * 2;
  unsigned short* rin  = (unsigned short*)p; p += NE * 2;
  unsigned short* keyb = (unsigned short*)p; p += NE * 2;
  unsigned short* valb = (unsigned short*)p; p += NE * 2;
  unsigned short* recb = (unsigned short*)p; p += NE * 2;
  // aliases: rwkv reuses kin (dead after key GEMM); s_* reuse vin (dead after
  // value GEMM). 3 x 2MB well within vin's 32MB.
  unsigned short* rwkv = kin;
  const long NS = (long)Bc * WKV_NCH * Cc;  // 524288
  float* s_num = (float*)vin;
  float* s_den = s_num + NS;
  float* s_mx  = s_den + NS;

  // 1. weights -> bf16
  {
    const int n4 = (int)(CC / 4);
    dim3 g((n4 + 255) / 256), b_(256);
    convert_bf16_kernel<<<g, b_, 0, stream>>>(Wk, Wk_b, n4);
    convert_bf16_kernel<<<g, b_, 0, stream>>>(Wv, Wv_b, n4);
    convert_bf16_kernel<<<g, b_, 0, stream>>>(Wr, Wr_b, n4);
    convert_bf16_kernel<<<g, b_, 0, stream>>>(Wo, Wo_b, n4);
  }

  // 2. time-mix + cast
  mix3_kernel<<<2048, 256, 0, stream>>>(x, tmk, tmv, tmr, kin, vin, rin, NE / 4);

  // 3. K/V/R GEMMs (K=1024), bf16 outputs
  {
    dim3 grid((unsigned)(BT / 128), (unsigned)(Cc / 128)), blk(256);
    gemm_bf16_2ph<unsigned short><<<grid, blk, 0, stream>>>(kin, Wk_b, keyb, Cc, Cc);
    gemm_bf16_2ph<unsigned short><<<grid, blk, 0, stream>>>(vin, Wv_b, valb, Cc, Cc);
    gemm_bf16_2ph<unsigned short><<<grid, blk, 0, stream>>>(rin, Wr_b, recb, Cc, Cc);
  }

  // 4. WKV chunked scan + sigmoid gate -> rwkv bf16
  wkv_phase1<<<2048, 256, 0, stream>>>(keyb, valb, td, s_num, s_den, s_mx);
  wkv_phase2<<<32, 256, 0, stream>>>(td, s_num, s_den, s_mx);
  wkv_phase3<<<2048, 256, 0, stream>>>(keyb, valb, recb, td, tf,
                                       s_num, s_den, s_mx, rwkv);

  // 5. output GEMM -> d_out (f32)
  {
    dim3 grid((unsigned)(BT / 128), (unsigned)(Cc / 128)), blk(256);
    gemm_bf16_2ph<float><<<grid, blk, 0, stream>>>(rwkv, Wo_b, (float*)d_out, Cc, Cc);
  }
}